// Round 21
// baseline (118.164 us; speedup 1.0000x reference)
//
#include <hip/hip_runtime.h>
#include <hip/hip_bf16.h>

#define BATCH 2
#define SEQ 2048
#define DMODEL 1024
#define NHEAD 16
#define DHEAD 64
#define NQKV 3072
#define DINNER 1024

typedef __attribute__((ext_vector_type(4))) short short4v;
typedef __attribute__((ext_vector_type(8))) short short8v;
typedef __attribute__((ext_vector_type(4))) float f32x4;

__device__ __forceinline__ unsigned short f2bf(float f) {
  union { float f; unsigned int u; } c; c.f = f;
  unsigned int u = c.u;
  u += 0x7fffu + ((u >> 16) & 1u);
  return (unsigned short)(u >> 16);
}

__device__ __forceinline__ float b2f(unsigned short u) {
  union { unsigned int i; float f; } c;
  c.i = ((unsigned int)u) << 16;
  return c.f;
}

__device__ __forceinline__ float exp2_hw(float x) {  // v_exp_f32: D = 2^S0
  float r;
  asm("v_exp_f32 %0, %1" : "=v"(r) : "v"(x));
  return r;
}

#define GL16(gp, lp)                                             \
  __builtin_amdgcn_global_load_lds(                              \
      (__attribute__((address_space(1))) void*)(gp),             \
      (__attribute__((address_space(3))) void*)(lp), 16, 0, 0)

// barrier with compile-time fences on BOTH sides (R19 race lesson)
#define FULL_BARRIER()                              \
  do {                                              \
    __builtin_amdgcn_sched_barrier(0);              \
    __builtin_amdgcn_s_barrier();                   \
    __builtin_amdgcn_sched_barrier(0);              \
  } while (0)

// ---------------- fused prep: both weight transposes + RMSNorm ---------------
__global__ __launch_bounds__(256) void prep_kernel(const float* __restrict__ x,
                                                   const float* __restrict__ gamma,
                                                   const float* __restrict__ w_qkv,
                                                   const float* __restrict__ w_out,
                                                   unsigned short* __restrict__ normed,
                                                   unsigned short* __restrict__ wqkvT,
                                                   unsigned short* __restrict__ woutT) {
  __shared__ float tile[32][33];
  __shared__ float wss[4];
  const int b = blockIdx.x;
  const int t = threadIdx.x;
  if (b < 4096) {  // transpose+cast
    const float* in;
    unsigned short* out;
    int K, N, blk;
    if (b < 3072) { in = w_qkv; out = wqkvT; K = DMODEL; N = NQKV; blk = b; }
    else          { in = w_out; out = woutT; K = DINNER; N = DMODEL; blk = b - 3072; }
    const int tiles_n = N >> 5;
    const int tn = blk % tiles_n;
    const int tk = blk / tiles_n;
    const int k0 = tk << 5, n0 = tn << 5;
#pragma unroll
    for (int p = 0; p < 4; p++) {
      const int e = p * 256 + t;
      const int r = e >> 5, c = e & 31;
      tile[r][c] = in[(size_t)(k0 + r) * N + n0 + c];
    }
    __syncthreads();
#pragma unroll
    for (int p = 0; p < 4; p++) {
      const int e = p * 256 + t;
      const int r = e >> 5, c = e & 31;
      out[(size_t)(n0 + r) * K + k0 + c] = f2bf(tile[c][r]);
    }
  } else {  // rmsnorm
    const int row = b - 4096;
    const float* xr = x + (size_t)row * DMODEL;
    float4 v = ((const float4*)xr)[t];
    float ss = v.x * v.x + v.y * v.y + v.z * v.z + v.w * v.w;
#pragma unroll
    for (int off = 1; off < 64; off <<= 1) ss += __shfl_xor(ss, off);
    if ((t & 63) == 0) wss[t >> 6] = ss;
    __syncthreads();
    const float tot = wss[0] + wss[1] + wss[2] + wss[3];
    float l2 = sqrtf(tot);
    l2 = fmaxf(l2, 1e-12f);
    const float s = 32.0f / l2;  // sqrt(1024)/l2
    const float4 gm = ((const float4*)gamma)[t];
    unsigned short o[4];
    o[0] = f2bf(v.x * s * gm.x);
    o[1] = f2bf(v.y * s * gm.y);
    o[2] = f2bf(v.z * s * gm.z);
    o[3] = f2bf(v.w * s * gm.w);
    unsigned short* op = normed + (size_t)row * DMODEL + t * 4;
    *(short4v*)op = *(short4v*)o;
  }
}

// ---------------- shared GEMM ring core: 128x128, 3-buf, counted vmcnt -------
#define BM 128
#define BN 128
#define BKT 32
#define TILE_E (BM * BKT)
#define RNT (DMODEL / BKT)  // 32

__device__ void gemm_ring(const unsigned short* __restrict__ A,
                          const unsigned short* __restrict__ Bt, int rowBase,
                          int colBase, unsigned short (*sA)[TILE_E],
                          unsigned short (*sB)[TILE_E], f32x4 acc[4][4]) {
  const int t = threadIdx.x;
  const int lane = t & 63, wave = t >> 6;
  const int l15 = lane & 15, g = lane >> 4;
  const int wr = (wave >> 1) * 64, wc = (wave & 1) * 64;
#pragma unroll
  for (int m = 0; m < 4; m++)
#pragma unroll
    for (int n = 0; n < 4; n++) acc[m][n] = (f32x4){0.f, 0.f, 0.f, 0.f};
  const int r0 = t >> 2, j0 = t & 3;
  const int swz = (r0 >> 1) & 3;  // same for row r0+64
  const unsigned short* Ag0 = A + (size_t)(rowBase + r0) * DMODEL + ((j0 ^ swz) * 8);
  const unsigned short* Ag1 = A + (size_t)(rowBase + r0 + 64) * DMODEL + ((j0 ^ swz) * 8);
  const unsigned short* Bg0 = Bt + (size_t)(colBase + r0) * DMODEL + ((j0 ^ swz) * 8);
  const unsigned short* Bg1 = Bt + (size_t)(colBase + r0 + 64) * DMODEL + ((j0 ^ swz) * 8);

#pragma unroll
  for (int tt = 0; tt < 2; ++tt) {
    GL16(Ag0 + tt * BKT, sA[tt] + t * 8);
    GL16(Ag1 + tt * BKT, sA[tt] + (t + 256) * 8);
    GL16(Bg0 + tt * BKT, sB[tt] + t * 8);
    GL16(Bg1 + tt * BKT, sB[tt] + (t + 256) * 8);
  }
  asm volatile("s_waitcnt vmcnt(4)" ::: "memory");  // tile 0 landed
  FULL_BARRIER();

  for (int kt = 0; kt < RNT; ++kt) {
    const unsigned short* sAc = sA[kt % 3];
    const unsigned short* sBc = sB[kt % 3];
    const bool pf = (kt + 2 < RNT);
    if (pf) {  // issue tile kt+2 into buf freed at end of iter kt-1
      const int nb = (kt + 2) % 3;
      const int ko = (kt + 2) * BKT;
      GL16(Ag0 + ko, sA[nb] + t * 8);
      GL16(Ag1 + ko, sA[nb] + (t + 256) * 8);
      GL16(Bg0 + ko, sB[nb] + t * 8);
      GL16(Bg1 + ko, sB[nb] + (t + 256) * 8);
    }
    short8v af[4], bf[4];
#pragma unroll
    for (int m = 0; m < 4; m++) {
      const int row = wr + m * 16 + l15;
      af[m] = *(const short8v*)(sAc + row * BKT + ((g ^ ((row >> 1) & 3)) * 8));
    }
#pragma unroll
    for (int n = 0; n < 4; n++) {
      const int row = wc + n * 16 + l15;
      bf[n] = *(const short8v*)(sBc + row * BKT + ((g ^ ((row >> 1) & 3)) * 8));
    }
    asm volatile("s_waitcnt lgkmcnt(0)" ::: "memory");
    __builtin_amdgcn_sched_barrier(0);
    __builtin_amdgcn_s_setprio(1);
#pragma unroll
    for (int m = 0; m < 4; m++)
#pragma unroll
      for (int n = 0; n < 4; n++)
        acc[m][n] = __builtin_amdgcn_mfma_f32_16x16x32_bf16(af[m], bf[n], acc[m][n], 0, 0, 0);
    __builtin_amdgcn_s_setprio(0);
    if (pf) asm volatile("s_waitcnt vmcnt(4)" ::: "memory");
    else    asm volatile("s_waitcnt vmcnt(0)" ::: "memory");
    FULL_BARRIER();
  }
}

// ---------------- QKV GEMM + scatter epilogue --------------------------------
__global__ __launch_bounds__(256, 3) void qkv_gemm_kernel(const unsigned short* __restrict__ A,
                                                          const unsigned short* __restrict__ Bt,
                                                          unsigned short* __restrict__ qb,
                                                          unsigned short* __restrict__ kb,
                                                          unsigned short* __restrict__ vtb) {
  __shared__ __align__(16) unsigned short sA[3][TILE_E];
  __shared__ __align__(16) unsigned short sB[3][TILE_E];
  const int nbn = NQKV / BN;  // 24
  const int bm = blockIdx.x / nbn, bn = blockIdx.x % nbn;
  f32x4 acc[4][4];
  gemm_ring(A, Bt, bm * BM, bn * BN, sA, sB, acc);
  const int t = threadIdx.x, lane = t & 63, wave = t >> 6;
  const int l15 = lane & 15, g = lane >> 4;
  const int wr = (wave >> 1) * 64, wc = (wave & 1) * 64;
#pragma unroll
  for (int m = 0; m < 4; m++)
#pragma unroll
    for (int n = 0; n < 4; n++) {
      const int col = bn * BN + wc + n * 16 + l15;
      const int part = col >> 10;
      const int h = (col >> 6) & 15;
      const int d = col & 63;
      const int row0 = bm * BM + wr + m * 16 + 4 * g;
      const int bb = row0 >> 11, i0 = row0 & 2047;
      if (part == 2) {
        const int ip = (i0 & ~31) | (((i0 >> 2) & 3) << 3) | (((i0 >> 4) & 1) << 2);
        union { short4v v; unsigned short u[4]; } pk;
#pragma unroll
        for (int r = 0; r < 4; r++) pk.u[r] = f2bf(acc[m][n][r]);
        *(short4v*)(vtb + ((size_t)(bb * NHEAD + h) * DHEAD + d) * SEQ + ip) = pk.v;
      } else {
#pragma unroll
        for (int r = 0; r < 4; r++) {
          const size_t idx = (((size_t)(bb * NHEAD + h)) * SEQ + i0 + r) * DHEAD + d;
          const float v = acc[m][n][r];
          if (part == 0) qb[idx] = f2bf(v * 0.18033688f);  // 0.125 * log2(e)
          else kb[idx] = f2bf(v);
        }
      }
    }
}

// ---------------- output GEMM: d_out = attn_out @ w_out ----------------------
__global__ __launch_bounds__(256, 3) void out_gemm_kernel(const unsigned short* __restrict__ A,
                                                          const unsigned short* __restrict__ Bt,
                                                          float* __restrict__ C) {
  __shared__ __align__(16) unsigned short sA[3][TILE_E];
  __shared__ __align__(16) unsigned short sB[3][TILE_E];
  const int nbn = DMODEL / BN;  // 8
  const int bm = blockIdx.x / nbn, bn = blockIdx.x % nbn;
  f32x4 acc[4][4];
  gemm_ring(A, Bt, bm * BM, bn * BN, sA, sB, acc);
  const int t = threadIdx.x, lane = t & 63, wave = t >> 6;
  const int l15 = lane & 15, g = lane >> 4;
  const int wr = (wave >> 1) * 64, wc = (wave & 1) * 64;
#pragma unroll
  for (int m = 0; m < 4; m++)
#pragma unroll
    for (int n = 0; n < 4; n++) {
      const int col = bn * BN + wc + n * 16 + l15;
#pragma unroll
      for (int r = 0; r < 4; r++) {
        const int row = bm * BM + wr + m * 16 + 4 * g + r;
        C[(size_t)row * DMODEL + col] = acc[m][n][r];
      }
    }
}

// ---------------- causal flash attention: split-K chunks, <=16 steps ---------
// Blocks = (bh, chunk): q-blocks 0..15 run whole key range (<=16 steps, write
// aout directly); q-blocks 16..31 are SPLIT into two key-range chunks, each an
// independent block with private flash state, writing normalized partials
// (O/l bf16, m+l f32) merged by attn_combine. LPT order (longest first),
// 5 blocks/CU (LDS 32KB x 5 = 160KB). All-GL16 staging, both-sides row&7
// swizzle, swapped QK/PV, exp2 softmax, MFMA ones-denominator.
__global__ __launch_bounds__(256, 5) void attn_partial_kernel(
    const unsigned short* __restrict__ qb, const unsigned short* __restrict__ kb,
    const unsigned short* __restrict__ vtb, unsigned short* __restrict__ ob,
    unsigned short* __restrict__ pO, float* __restrict__ pML) {
  __shared__ __align__(16) unsigned short sK[2][64 * 64];
  __shared__ __align__(16) unsigned short sV[2][64 * 64];
  const int t = threadIdx.x, lane = t & 63, wave = t >> 6;
  const int l15 = lane & 15, g = lane >> 4;
  const int bh = blockIdx.x & 31;
  const int ord = blockIdx.x >> 5;  // 0..47, LPT: long chunks first
  int qblk, s0, s1, half;
  bool split;
  if (ord < 32) {  // split halves of q-blocks 31..16
    const int j = 31 - ord;
    qblk = 16 + (j >> 1);
    half = j & 1;
    const int nst = qblk + 1;
    s0 = half ? (nst >> 1) : 0;
    s1 = half ? nst : (nst >> 1);
    split = true;
  } else {  // whole q-blocks 15..0
    qblk = 47 - ord;
    half = 0;
    s0 = 0;
    s1 = qblk + 1;
    split = false;
  }
  const int qrow = qblk * 64 + wave * 16 + l15;
  const unsigned short* qptr = qb + (size_t)bh * SEQ * DHEAD;
  const unsigned short* kptr = kb + (size_t)bh * SEQ * DHEAD;
  const unsigned short* vtptr = vtb + (size_t)bh * DHEAD * SEQ;

  const int kr0 = t >> 3, kj0 = ((t & 7) ^ (kr0 & 7)) * 8;
  const int kr1 = kr0 + 32, kj1 = ((t & 7) ^ (kr1 & 7)) * 8;

  short8v qf[2];
#pragma unroll
  for (int kk = 0; kk < 2; kk++)
    qf[kk] = *(const short8v*)(qptr + (size_t)qrow * DHEAD + kk * 32 + 8 * g);

  union { short8v v; unsigned short u[8]; } ones;
#pragma unroll
  for (int j = 0; j < 8; j++) ones.u[j] = 0x3F80;

  float rm = -__builtin_inff();
  f32x4 acc_l = (f32x4){0.f, 0.f, 0.f, 0.f};
  f32x4 acc_o[4];
#pragma unroll
  for (int df = 0; df < 4; df++) acc_o[df] = (f32x4){0.f, 0.f, 0.f, 0.f};

  // prologue: stage tile s0 (K and V) via GL16
  {
    const int kb0 = s0 * 64;
    GL16(kptr + (size_t)(kb0 + kr0) * DHEAD + kj0, sK[0] + t * 8);
    GL16(kptr + (size_t)(kb0 + kr1) * DHEAD + kj1, sK[0] + (t + 256) * 8);
    GL16(vtptr + (size_t)kr0 * SEQ + kb0 + kj0, sV[0] + t * 8);
    GL16(vtptr + (size_t)kr1 * SEQ + kb0 + kj1, sV[0] + (t + 256) * 8);
  }
  asm volatile("s_waitcnt vmcnt(0)" ::: "memory");
  FULL_BARRIER();

  int cur = 0;
  for (int s = s0; s < s1; ++s, cur ^= 1) {
    const int nxt = cur ^ 1;
    const bool more = (s + 1 < s1);
    if (more) {
      const int k0n = (s + 1) * 64;
      GL16(kptr + (size_t)(k0n + kr0) * DHEAD + kj0, sK[nxt] + t * 8);
      GL16(kptr + (size_t)(k0n + kr1) * DHEAD + kj1, sK[nxt] + (t + 256) * 8);
      GL16(vtptr + (size_t)kr0 * SEQ + k0n + kj0, sV[nxt] + t * 8);
      GL16(vtptr + (size_t)kr1 * SEQ + k0n + kj1, sV[nxt] + (t + 256) * 8);
    }
    {
      const int k0 = s * 64;
      const unsigned short* sKc = sK[cur];
      const unsigned short* sVc = sV[cur];
      short8v kf[4][2];
#pragma unroll
      for (int n4 = 0; n4 < 4; n4++) {
        const int row = n4 * 16 + l15;
#pragma unroll
        for (int kk = 0; kk < 2; kk++)
          kf[n4][kk] = *(const short8v*)(sKc + row * 64 + (((kk * 4 + g) ^ (row & 7)) * 8));
      }
      f32x4 s4[4];
#pragma unroll
      for (int n4 = 0; n4 < 4; n4++) s4[n4] = (f32x4){0.f, 0.f, 0.f, 0.f};
#pragma unroll
      for (int n4 = 0; n4 < 4; n4++)
#pragma unroll
        for (int kk = 0; kk < 2; kk++)
          s4[n4] = __builtin_amdgcn_mfma_f32_16x16x32_bf16(kf[n4][kk], qf[kk],
                                                           s4[n4], 0, 0, 0);
      if (s == qblk) {  // diagonal step: causal mask
#pragma unroll
        for (int n4 = 0; n4 < 4; n4++)
#pragma unroll
          for (int r = 0; r < 4; r++)
            if (k0 + n4 * 16 + 4 * g + r > qrow) s4[n4][r] = -__builtin_inff();
      }
      float mx = s4[0][0];
#pragma unroll
      for (int n4 = 0; n4 < 4; n4++)
#pragma unroll
        for (int r = 0; r < 4; r++)
          if (n4 || r) mx = fmaxf(mx, s4[n4][r]);
      if (!__all(mx <= rm)) {
        mx = fmaxf(mx, __shfl_xor(mx, 16));
        mx = fmaxf(mx, __shfl_xor(mx, 32));
        const float nm = fmaxf(rm, mx);
        const float al = exp2_hw(rm - nm);
        rm = nm;
#pragma unroll
        for (int r = 0; r < 4; r++) acc_l[r] *= al;
#pragma unroll
        for (int df = 0; df < 4; df++)
#pragma unroll
          for (int r = 0; r < 4; r++) acc_o[df][r] *= al;
      }
#pragma unroll
      for (int n4 = 0; n4 < 4; n4++)
#pragma unroll
        for (int r = 0; r < 4; r++) s4[n4][r] = exp2_hw(s4[n4][r] - rm);
      unsigned int pw[8];
#pragma unroll
      for (int n4 = 0; n4 < 4; n4++) {
        asm("v_cvt_pk_bf16_f32 %0, %1, %2"
            : "=v"(pw[n4 * 2]) : "v"(s4[n4][0]), "v"(s4[n4][1]));
        asm("v_cvt_pk_bf16_f32 %0, %1, %2"
            : "=v"(pw[n4 * 2 + 1]) : "v"(s4[n4][2]), "v"(s4[n4][3]));
      }
      union { short8v v; unsigned int wd[4]; } paA, paB;
      paA.wd[0] = pw[0]; paA.wd[1] = pw[1]; paA.wd[2] = pw[2]; paA.wd[3] = pw[3];
      paB.wd[0] = pw[4]; paB.wd[1] = pw[5]; paB.wd[2] = pw[6]; paB.wd[3] = pw[7];
      acc_l = __builtin_amdgcn_mfma_f32_16x16x32_bf16(ones.v, paA.v, acc_l, 0, 0, 0);
      acc_l = __builtin_amdgcn_mfma_f32_16x16x32_bf16(ones.v, paB.v, acc_l, 0, 0, 0);
#pragma unroll
      for (int df = 0; df < 4; df++) {
        const int row = df * 16 + l15;
        const short8v vfa = *(const short8v*)(sVc + row * 64 + (((g) ^ (row & 7)) * 8));
        acc_o[df] = __builtin_amdgcn_mfma_f32_16x16x32_bf16(vfa, paA.v, acc_o[df], 0, 0, 0);
        const short8v vfb = *(const short8v*)(sVc + row * 64 + (((4 + g) ^ (row & 7)) * 8));
        acc_o[df] = __builtin_amdgcn_mfma_f32_16x16x32_bf16(vfb, paB.v, acc_o[df], 0, 0, 0);
      }
    }
    if (more) {
      asm volatile("s_waitcnt vmcnt(0) lgkmcnt(0)" ::: "memory");
      FULL_BARRIER();
    }
  }

  const float l = acc_l[0];
  const float inv = 1.0f / l;
  if (!split) {  // final: normalize + write aout
    const int bb = bh >> 4, hh = bh & 15;
#pragma unroll
    for (int df = 0; df < 4; df++) {
      union { short4v v; unsigned short u[4]; } pk4;
#pragma unroll
      for (int r = 0; r < 4; r++) pk4.u[r] = f2bf(acc_o[df][r] * inv);
      *(short4v*)(ob + ((size_t)bb * SEQ + qrow) * DINNER + hh * DHEAD + df * 16 + 4 * g) =
          pk4.v;
    }
  } else {  // write normalized partial (O/l bf16) + m,l
    const int chunk = (bh * 16 + (qblk - 16)) * 2 + half;
    const int q = wave * 16 + l15;
    unsigned short* po = pO + ((size_t)(chunk * 64 + q)) * 64;
#pragma unroll
    for (int df = 0; df < 4; df++) {
      union { short4v v; unsigned short u[4]; } pk4;
#pragma unroll
      for (int r = 0; r < 4; r++) pk4.u[r] = f2bf(acc_o[df][r] * inv);
      *(short4v*)(po + df * 16 + 4 * g) = pk4.v;
    }
    if (g == 0) {
      float* ml = pML + (size_t)chunk * 128 + q * 2;
      ml[0] = rm;
      ml[1] = l;
    }
  }
}

// ---------------- combine: merge two normalized partials per (bh, qblk) ------
__global__ __launch_bounds__(256) void attn_combine_kernel(
    const unsigned short* __restrict__ pO, const float* __restrict__ pML,
    unsigned short* __restrict__ ob) {
  const int blk = blockIdx.x;  // 0..511
  const int bh = blk & 31, qi = blk >> 5;  // qi 0..15
  const int qblk = 16 + qi;
  const int t = threadIdx.x;
  const int q = t >> 2, ds = (t & 3) * 16;
  const int chunk0 = (bh * 16 + qi) * 2;
  const float m0 = pML[(size_t)chunk0 * 128 + q * 2];
  const float l0 = pML[(size_t)chunk0 * 128 + q * 2 + 1];
  const float m1 = pML[(size_t)(chunk0 + 1) * 128 + q * 2];
  const float l1 = pML[(size_t)(chunk0 + 1) * 128 + q * 2 + 1];
  const float M = fmaxf(m0, m1);
  const float w0 = exp2_hw(m0 - M) * l0;
  const float w1 = exp2_hw(m1 - M) * l1;
  const float inv = 1.0f / (w0 + w1);
  const unsigned short* o0 = pO + ((size_t)(chunk0 * 64 + q)) * 64 + ds;
  const unsigned short* o1 = pO + ((size_t)((chunk0 + 1) * 64 + q)) * 64 + ds;
  union { short8v v; unsigned short u[8]; } a0, a1, b0, b1, r0, r1;
  a0.v = *(const short8v*)o0;
  b0.v = *(const short8v*)(o0 + 8);
  a1.v = *(const short8v*)o1;
  b1.v = *(const short8v*)(o1 + 8);
#pragma unroll
  for (int j = 0; j < 8; j++) {
    r0.u[j] = f2bf((w0 * b2f(a0.u[j]) + w1 * b2f(a1.u[j])) * inv);
    r1.u[j] = f2bf((w0 * b2f(b0.u[j]) + w1 * b2f(b1.u[j])) * inv);
  }
  const int bb = bh >> 4, hh = bh & 15;
  unsigned short* op = ob + ((size_t)bb * SEQ + qblk * 64 + q) * DINNER + hh * DHEAD + ds;
  *(short8v*)op = r0.v;
  *(short8v*)(op + 8) = r1.v;
}

extern "C" void kernel_launch(void* const* d_in, const int* in_sizes, int n_in,
                              void* d_out, int out_size, void* d_ws, size_t ws_size,
                              hipStream_t stream) {
  (void)in_sizes; (void)n_in; (void)out_size; (void)ws_size;
  const float* x = (const float*)d_in[0];
  const float* gamma = (const float*)d_in[1];
  const float* w_qkv = (const float*)d_in[2];
  const float* w_out = (const float*)d_in[3];
  float* out = (float*)d_out;
  char* ws = (char*)d_ws;
  unsigned short* wqkvT = (unsigned short*)(ws);                // 6291456 B
  unsigned short* woutT = (unsigned short*)(ws + 6291456);      // 2097152 B
  unsigned short* normed = (unsigned short*)(ws + 8388608);     // 8388608 B
  unsigned short* qbuf = (unsigned short*)(ws + 16777216);      // 8388608 B
  unsigned short* kbuf = (unsigned short*)(ws + 25165824);      // 8388608 B
  unsigned short* vtbuf = (unsigned short*)(ws + 33554432);     // 8388608 B (permuted V^T)
  unsigned short* aout = (unsigned short*)(ws + 41943040);      // 8388608 B
  // attention partials REUSE regions dead after qkv_gemm (rewritten by prep
  // each replay -> deterministic): pO = normed region (exactly 8 MB),
  // pML = head of wqkvT region (512 KB).
  unsigned short* pO = normed;
  float* pML = (float*)ws;

  hipLaunchKernelGGL(prep_kernel, dim3(8192), dim3(256), 0, stream,
                     x, gamma, w_qkv, w_out, normed, wqkvT, woutT);
  hipLaunchKernelGGL(qkv_gemm_kernel, dim3((BATCH * SEQ / BM) * (NQKV / BN)), dim3(256), 0,
                     stream, normed, wqkvT, qbuf, kbuf, vtbuf);
  hipLaunchKernelGGL(attn_partial_kernel, dim3(BATCH * NHEAD * 48), dim3(256), 0, stream,
                     qbuf, kbuf, vtbuf, aout, pO, pML);
  hipLaunchKernelGGL(attn_combine_kernel, dim3(BATCH * NHEAD * 16), dim3(256), 0, stream,
                     pO, pML, aout);
  hipLaunchKernelGGL(out_gemm_kernel, dim3((BATCH * SEQ / BM) * (DMODEL / BN)), dim3(256), 0,
                     stream, aout, woutT, out);
}

// Round 22
// 109.774 us; speedup vs baseline: 1.0764x; 1.0764x over previous
//
#include <hip/hip_runtime.h>
#include <hip/hip_bf16.h>

#define BATCH 2
#define SEQ 2048
#define DMODEL 1024
#define NHEAD 16
#define DHEAD 64
#define NQKV 3072
#define DINNER 1024

typedef __attribute__((ext_vector_type(4))) short short4v;
typedef __attribute__((ext_vector_type(8))) short short8v;
typedef __attribute__((ext_vector_type(4))) float f32x4;

__device__ __forceinline__ unsigned short f2bf(float f) {
  union { float f; unsigned int u; } c; c.f = f;
  unsigned int u = c.u;
  u += 0x7fffu + ((u >> 16) & 1u);
  return (unsigned short)(u >> 16);
}

__device__ __forceinline__ float exp2_hw(float x) {  // v_exp_f32: D = 2^S0
  float r;
  asm("v_exp_f32 %0, %1" : "=v"(r) : "v"(x));
  return r;
}

__device__ __forceinline__ short8v load_frag(const unsigned short* p0, const unsigned short* p1) {
  union { short8v v8; short4v v4[2]; } u;
  u.v4[0] = *(const short4v*)p0;
  u.v4[1] = *(const short4v*)p1;
  return u.v8;
}

#define GL16(gp, lp)                                             \
  __builtin_amdgcn_global_load_lds(                              \
      (__attribute__((address_space(1))) void*)(gp),             \
      (__attribute__((address_space(3))) void*)(lp), 16, 0, 0)

// ---------------- fused prep: both weight transposes + RMSNorm ---------------
__global__ __launch_bounds__(256) void prep_kernel(const float* __restrict__ x,
                                                   const float* __restrict__ gamma,
                                                   const float* __restrict__ w_qkv,
                                                   const float* __restrict__ w_out,
                                                   unsigned short* __restrict__ normed,
                                                   unsigned short* __restrict__ wqkvT,
                                                   unsigned short* __restrict__ woutT) {
  __shared__ float tile[32][33];
  __shared__ float wss[4];
  const int b = blockIdx.x;
  const int t = threadIdx.x;
  if (b < 4096) {  // transpose+cast
    const float* in;
    unsigned short* out;
    int K, N, blk;
    if (b < 3072) { in = w_qkv; out = wqkvT; K = DMODEL; N = NQKV; blk = b; }
    else          { in = w_out; out = woutT; K = DINNER; N = DMODEL; blk = b - 3072; }
    const int tiles_n = N >> 5;
    const int tn = blk % tiles_n;
    const int tk = blk / tiles_n;
    const int k0 = tk << 5, n0 = tn << 5;
#pragma unroll
    for (int p = 0; p < 4; p++) {
      const int e = p * 256 + t;
      const int r = e >> 5, c = e & 31;
      tile[r][c] = in[(size_t)(k0 + r) * N + n0 + c];
    }
    __syncthreads();
#pragma unroll
    for (int p = 0; p < 4; p++) {
      const int e = p * 256 + t;
      const int r = e >> 5, c = e & 31;
      out[(size_t)(n0 + r) * K + k0 + c] = f2bf(tile[c][r]);
    }
  } else {  // rmsnorm
    const int row = b - 4096;
    const float* xr = x + (size_t)row * DMODEL;
    float4 v = ((const float4*)xr)[t];
    float ss = v.x * v.x + v.y * v.y + v.z * v.z + v.w * v.w;
#pragma unroll
    for (int off = 1; off < 64; off <<= 1) ss += __shfl_xor(ss, off);
    if ((t & 63) == 0) wss[t >> 6] = ss;
    __syncthreads();
    const float tot = wss[0] + wss[1] + wss[2] + wss[3];
    float l2 = sqrtf(tot);
    l2 = fmaxf(l2, 1e-12f);
    const float s = 32.0f / l2;  // sqrt(1024)/l2
    const float4 gm = ((const float4*)gamma)[t];
    unsigned short o[4];
    o[0] = f2bf(v.x * s * gm.x);
    o[1] = f2bf(v.y * s * gm.y);
    o[2] = f2bf(v.z * s * gm.z);
    o[3] = f2bf(v.w * s * gm.w);
    unsigned short* op = normed + (size_t)row * DMODEL + t * 4;
    *(short4v*)op = *(short4v*)o;
  }
}

// ---------------- shared GEMM ring core: 128x128, 3-buf, counted vmcnt -------
// One raw s_barrier per K-step, preceded by counted vmcnt(4) (tile kt+1
// certified; kt+2's 4 loads stay in flight -- never drained mid-loop). Tile
// kt+2 issued into the buffer freed at the end of iter kt-1 (race-free by
// program order + barrier). Corrected (row>>1)&3 both-sides swizzle (R16:
// SQ_LDS_BANK_CONFLICT == 0).
#define BM 128
#define BN 128
#define BKT 32
#define TILE_E (BM * BKT)
#define RNT (DMODEL / BKT)  // 32 (K = 1024 for both GEMMs)

__device__ void gemm_ring(const unsigned short* __restrict__ A,
                          const unsigned short* __restrict__ Bt, int rowBase,
                          int colBase, unsigned short (*sA)[TILE_E],
                          unsigned short (*sB)[TILE_E], f32x4 acc[4][4]) {
  const int t = threadIdx.x;
  const int lane = t & 63, wave = t >> 6;
  const int l15 = lane & 15, g = lane >> 4;
  const int wr = (wave >> 1) * 64, wc = (wave & 1) * 64;
#pragma unroll
  for (int m = 0; m < 4; m++)
#pragma unroll
    for (int n = 0; n < 4; n++) acc[m][n] = (f32x4){0.f, 0.f, 0.f, 0.f};
  const int r0 = t >> 2, j0 = t & 3;
  const int swz = (r0 >> 1) & 3;  // same for row r0+64
  const unsigned short* Ag0 = A + (size_t)(rowBase + r0) * DMODEL + ((j0 ^ swz) * 8);
  const unsigned short* Ag1 = A + (size_t)(rowBase + r0 + 64) * DMODEL + ((j0 ^ swz) * 8);
  const unsigned short* Bg0 = Bt + (size_t)(colBase + r0) * DMODEL + ((j0 ^ swz) * 8);
  const unsigned short* Bg1 = Bt + (size_t)(colBase + r0 + 64) * DMODEL + ((j0 ^ swz) * 8);

  // prologue: stage tiles 0 and 1 (8 GL16/thread outstanding)
#pragma unroll
  for (int tt = 0; tt < 2; ++tt) {
    GL16(Ag0 + tt * BKT, sA[tt] + t * 8);
    GL16(Ag1 + tt * BKT, sA[tt] + (t + 256) * 8);
    GL16(Bg0 + tt * BKT, sB[tt] + t * 8);
    GL16(Bg1 + tt * BKT, sB[tt] + (t + 256) * 8);
  }
  asm volatile("s_waitcnt vmcnt(4)" ::: "memory");  // tile 0 landed
  __builtin_amdgcn_sched_barrier(0);
  __builtin_amdgcn_s_barrier();

  for (int kt = 0; kt < RNT; ++kt) {
    const unsigned short* sAc = sA[kt % 3];
    const unsigned short* sBc = sB[kt % 3];
    const bool pf = (kt + 2 < RNT);
    if (pf) {  // issue tile kt+2 into buf freed at end of iter kt-1
      const int nb = (kt + 2) % 3;
      const int ko = (kt + 2) * BKT;
      GL16(Ag0 + ko, sA[nb] + t * 8);
      GL16(Ag1 + ko, sA[nb] + (t + 256) * 8);
      GL16(Bg0 + ko, sB[nb] + t * 8);
      GL16(Bg1 + ko, sB[nb] + (t + 256) * 8);
    }
    short8v af[4], bf[4];
#pragma unroll
    for (int m = 0; m < 4; m++) {
      const int row = wr + m * 16 + l15;
      af[m] = *(const short8v*)(sAc + row * BKT + ((g ^ ((row >> 1) & 3)) * 8));
    }
#pragma unroll
    for (int n = 0; n < 4; n++) {
      const int row = wc + n * 16 + l15;
      bf[n] = *(const short8v*)(sBc + row * BKT + ((g ^ ((row >> 1) & 3)) * 8));
    }
    asm volatile("s_waitcnt lgkmcnt(0)" ::: "memory");
    __builtin_amdgcn_sched_barrier(0);
    __builtin_amdgcn_s_setprio(1);
#pragma unroll
    for (int m = 0; m < 4; m++)
#pragma unroll
      for (int n = 0; n < 4; n++)
        acc[m][n] = __builtin_amdgcn_mfma_f32_16x16x32_bf16(af[m], bf[n], acc[m][n], 0, 0, 0);
    __builtin_amdgcn_s_setprio(0);
    // certify tile kt+1; keep kt+2's 4 loads in flight (never drain mid-loop)
    if (pf) asm volatile("s_waitcnt vmcnt(4)" ::: "memory");
    else    asm volatile("s_waitcnt vmcnt(0)" ::: "memory");
    __builtin_amdgcn_sched_barrier(0);
    __builtin_amdgcn_s_barrier();
  }
}

// ---------------- QKV GEMM + scatter epilogue --------------------------------
// q pre-scaled by d^-0.5 * log2(e) (exp2-domain softmax); V^T stored
// column-permuted so attn's PV B-fragment is one contiguous b128.
__global__ __launch_bounds__(256, 3) void qkv_gemm_kernel(const unsigned short* __restrict__ A,
                                                          const unsigned short* __restrict__ Bt,
                                                          unsigned short* __restrict__ qb,
                                                          unsigned short* __restrict__ kb,
                                                          unsigned short* __restrict__ vtb) {
  __shared__ __align__(16) unsigned short sA[3][TILE_E];  // 3 x 8KB
  __shared__ __align__(16) unsigned short sB[3][TILE_E];  // 3 x 8KB (48KB)
  const int nbn = NQKV / BN;  // 24
  const int bm = blockIdx.x / nbn, bn = blockIdx.x % nbn;
  f32x4 acc[4][4];
  gemm_ring(A, Bt, bm * BM, bn * BN, sA, sB, acc);
  const int t = threadIdx.x, lane = t & 63, wave = t >> 6;
  const int l15 = lane & 15, g = lane >> 4;
  const int wr = (wave >> 1) * 64, wc = (wave & 1) * 64;
#pragma unroll
  for (int m = 0; m < 4; m++)
#pragma unroll
    for (int n = 0; n < 4; n++) {
      const int col = bn * BN + wc + n * 16 + l15;
      const int part = col >> 10;
      const int h = (col >> 6) & 15;
      const int d = col & 63;
      const int row0 = bm * BM + wr + m * 16 + 4 * g;
      const int bb = row0 >> 11, i0 = row0 & 2047;
      if (part == 2) {
        const int ip = (i0 & ~31) | (((i0 >> 2) & 3) << 3) | (((i0 >> 4) & 1) << 2);
        union { short4v v; unsigned short u[4]; } pk;
#pragma unroll
        for (int r = 0; r < 4; r++) pk.u[r] = f2bf(acc[m][n][r]);
        *(short4v*)(vtb + ((size_t)(bb * NHEAD + h) * DHEAD + d) * SEQ + ip) = pk.v;
      } else {
#pragma unroll
        for (int r = 0; r < 4; r++) {
          const size_t idx = (((size_t)(bb * NHEAD + h)) * SEQ + i0 + r) * DHEAD + d;
          const float v = acc[m][n][r];
          if (part == 0) qb[idx] = f2bf(v * 0.18033688f);  // 0.125 * log2(e)
          else kb[idx] = f2bf(v);
        }
      }
    }
}

// ---------------- output GEMM: d_out = attn_out @ w_out ----------------------
__global__ __launch_bounds__(256, 3) void out_gemm_kernel(const unsigned short* __restrict__ A,
                                                          const unsigned short* __restrict__ Bt,
                                                          float* __restrict__ C) {
  __shared__ __align__(16) unsigned short sA[3][TILE_E];
  __shared__ __align__(16) unsigned short sB[3][TILE_E];
  const int nbn = DMODEL / BN;  // 8
  const int bm = blockIdx.x / nbn, bn = blockIdx.x % nbn;
  f32x4 acc[4][4];
  gemm_ring(A, Bt, bm * BM, bn * BN, sA, sB, acc);
  const int t = threadIdx.x, lane = t & 63, wave = t >> 6;
  const int l15 = lane & 15, g = lane >> 4;
  const int wr = (wave >> 1) * 64, wc = (wave & 1) * 64;
#pragma unroll
  for (int m = 0; m < 4; m++)
#pragma unroll
    for (int n = 0; n < 4; n++) {
      const int col = bn * BN + wc + n * 16 + l15;
#pragma unroll
      for (int r = 0; r < 4; r++) {
        const int row = bm * BM + wr + m * 16 + 4 * g + r;
        C[(size_t)row * DMODEL + col] = acc[m][n][r];
      }
    }
}

// ---------------- causal flash attention: 64-row blocks, 4 blocks/CU ---------
// R9 structure + exp2 softmax + MFMA ones-denominator + producer-permuted V^T
// (PV B-frags = single b128, bank-uniform). K via global_load_lds + both-sides
// XOR swizzle. Swapped QK/PV keep softmax lane-local (q = l15).
__global__ __launch_bounds__(256, 4) void attn_kernel(const unsigned short* __restrict__ qb,
                                                      const unsigned short* __restrict__ kb,
                                                      const unsigned short* __restrict__ vtb,
                                                      unsigned short* __restrict__ ob) {
  __shared__ __align__(16) unsigned short sK[2][64 * 64];  // 8KB each, swizzled
  __shared__ __align__(16) unsigned short sV[2][64 * 72];  // padded rows (144B)
  const int t = threadIdx.x, lane = t & 63, wave = t >> 6;
  const int l15 = lane & 15, g = lane >> 4;
  const int bh = blockIdx.x & 31;        // low bits -> same-bh blocks same XCD
  const int qord = blockIdx.x >> 5;      // 0..31
  const int qblk = (qord < 8) ? 31 - qord
                 : (qord < 16) ? qord - 8
                 : (qord < 24) ? 39 - qord
                 : qord - 16;
  const int qrow = qblk * 64 + wave * 16 + l15;
  const unsigned short* qptr = qb + (size_t)bh * SEQ * DHEAD;
  const unsigned short* kptr = kb + (size_t)bh * SEQ * DHEAD;
  const unsigned short* vtptr = vtb + (size_t)bh * DHEAD * SEQ;

  const int kr0 = t >> 3, kj0 = ((t & 7) ^ (kr0 & 7)) * 8;
  const int kr1 = (t + 256) >> 3, kj1 = ((t & 7) ^ (kr1 & 7)) * 8;
  const int vr0 = t >> 3, vo0 = (t & 7) * 8;
  const int vr1 = (t + 256) >> 3, vo1 = (t & 7) * 8;

  short8v qf[2];
#pragma unroll
  for (int kk = 0; kk < 2; kk++)
    qf[kk] = *(const short8v*)(qptr + (size_t)qrow * DHEAD + kk * 32 + 8 * g);

  union { short8v v; unsigned short u[8]; } ones;
#pragma unroll
  for (int j = 0; j < 8; j++) ones.u[j] = 0x3F80;

  float rm = -__builtin_inff();
  f32x4 acc_l = (f32x4){0.f, 0.f, 0.f, 0.f};
  f32x4 acc_o[4];
#pragma unroll
  for (int df = 0; df < 4; df++) acc_o[df] = (f32x4){0.f, 0.f, 0.f, 0.f};

  const int nsteps = qblk + 1;

  GL16(kptr + (size_t)kr0 * DHEAD + kj0, sK[0] + t * 8);
  GL16(kptr + (size_t)kr1 * DHEAD + kj1, sK[0] + (t + 256) * 8);
  {
    short8v va = *(const short8v*)(vtptr + (size_t)vr0 * SEQ + vo0);
    short8v vb = *(const short8v*)(vtptr + (size_t)vr1 * SEQ + vo1);
    *(short8v*)(sV[0] + vr0 * 72 + vo0) = va;
    *(short8v*)(sV[0] + vr1 * 72 + vo1) = vb;
  }
  __syncthreads();

  int cur = 0;
  for (int s = 0; s < nsteps; ++s, cur ^= 1) {
    const int nxt = cur ^ 1;
    const bool more = (s + 1 < nsteps);
    short8v va, vb;
    if (more) {
      const int k0n = (s + 1) * 64;
      GL16(kptr + (size_t)(k0n + kr0) * DHEAD + kj0, sK[nxt] + t * 8);
      GL16(kptr + (size_t)(k0n + kr1) * DHEAD + kj1, sK[nxt] + (t + 256) * 8);
      va = *(const short8v*)(vtptr + (size_t)vr0 * SEQ + k0n + vo0);
      vb = *(const short8v*)(vtptr + (size_t)vr1 * SEQ + k0n + vo1);
    }
    {
      const int k0 = s * 64;
      const unsigned short* sKc = sK[cur];
      const unsigned short* sVc = sV[cur];
      short8v kf[4][2];
#pragma unroll
      for (int n4 = 0; n4 < 4; n4++) {
        const int row = n4 * 16 + l15;
#pragma unroll
        for (int kk = 0; kk < 2; kk++)
          kf[n4][kk] = *(const short8v*)(sKc + row * 64 + (((kk * 4 + g) ^ (row & 7)) * 8));
      }
      f32x4 s4[4];
#pragma unroll
      for (int n4 = 0; n4 < 4; n4++) s4[n4] = (f32x4){0.f, 0.f, 0.f, 0.f};
#pragma unroll
      for (int n4 = 0; n4 < 4; n4++)
#pragma unroll
        for (int kk = 0; kk < 2; kk++)
          s4[n4] = __builtin_amdgcn_mfma_f32_16x16x32_bf16(kf[n4][kk], qf[kk],
                                                           s4[n4], 0, 0, 0);
      if (s == nsteps - 1) {
#pragma unroll
        for (int n4 = 0; n4 < 4; n4++)
#pragma unroll
          for (int r = 0; r < 4; r++)
            if (k0 + n4 * 16 + 4 * g + r > qrow) s4[n4][r] = -__builtin_inff();
      }
      float mx = s4[0][0];
#pragma unroll
      for (int n4 = 0; n4 < 4; n4++)
#pragma unroll
        for (int r = 0; r < 4; r++)
          if (n4 || r) mx = fmaxf(mx, s4[n4][r]);
      if (!__all(mx <= rm)) {
        mx = fmaxf(mx, __shfl_xor(mx, 16));
        mx = fmaxf(mx, __shfl_xor(mx, 32));
        const float nm = fmaxf(rm, mx);
        const float al = exp2_hw(rm - nm);
        rm = nm;
#pragma unroll
        for (int r = 0; r < 4; r++) acc_l[r] *= al;
#pragma unroll
        for (int df = 0; df < 4; df++)
#pragma unroll
          for (int r = 0; r < 4; r++) acc_o[df][r] *= al;
      }
#pragma unroll
      for (int n4 = 0; n4 < 4; n4++)
#pragma unroll
        for (int r = 0; r < 4; r++) s4[n4][r] = exp2_hw(s4[n4][r] - rm);
      unsigned int pw[8];
#pragma unroll
      for (int n4 = 0; n4 < 4; n4++) {
        asm("v_cvt_pk_bf16_f32 %0, %1, %2"
            : "=v"(pw[n4 * 2]) : "v"(s4[n4][0]), "v"(s4[n4][1]));
        asm("v_cvt_pk_bf16_f32 %0, %1, %2"
            : "=v"(pw[n4 * 2 + 1]) : "v"(s4[n4][2]), "v"(s4[n4][3]));
      }
      union { short8v v; unsigned int wd[4]; } paA, paB;
      paA.wd[0] = pw[0]; paA.wd[1] = pw[1]; paA.wd[2] = pw[2]; paA.wd[3] = pw[3];
      paB.wd[0] = pw[4]; paB.wd[1] = pw[5]; paB.wd[2] = pw[6]; paB.wd[3] = pw[7];
      acc_l = __builtin_amdgcn_mfma_f32_16x16x32_bf16(ones.v, paA.v, acc_l, 0, 0, 0);
      acc_l = __builtin_amdgcn_mfma_f32_16x16x32_bf16(ones.v, paB.v, acc_l, 0, 0, 0);
#pragma unroll
      for (int df = 0; df < 4; df++) {
        const unsigned short* pv = sVc + (df * 16 + l15) * 72 + 8 * g;
        const short8v vfa = *(const short8v*)(pv);
        acc_o[df] = __builtin_amdgcn_mfma_f32_16x16x32_bf16(vfa, paA.v, acc_o[df], 0, 0, 0);
        const short8v vfb = *(const short8v*)(pv + 32);
        acc_o[df] = __builtin_amdgcn_mfma_f32_16x16x32_bf16(vfb, paB.v, acc_o[df], 0, 0, 0);
      }
    }
    if (more) {
      *(short8v*)(sV[nxt] + vr0 * 72 + vo0) = va;
      *(short8v*)(sV[nxt] + vr1 * 72 + vo1) = vb;
    }
    __syncthreads();
  }

  const int bb = bh >> 4, hh = bh & 15;
  const float inv = 1.0f / acc_l[0];
#pragma unroll
  for (int df = 0; df < 4; df++) {
    union { short4v v; unsigned short u[4]; } pk4;
#pragma unroll
    for (int r = 0; r < 4; r++) pk4.u[r] = f2bf(acc_o[df][r] * inv);
    *(short4v*)(ob + ((size_t)bb * SEQ + qrow) * DINNER + hh * DHEAD + df * 16 + 4 * g) =
        pk4.v;
  }
}

extern "C" void kernel_launch(void* const* d_in, const int* in_sizes, int n_in,
                              void* d_out, int out_size, void* d_ws, size_t ws_size,
                              hipStream_t stream) {
  (void)in_sizes; (void)n_in; (void)out_size; (void)ws_size;
  const float* x = (const float*)d_in[0];
  const float* gamma = (const float*)d_in[1];
  const float* w_qkv = (const float*)d_in[2];
  const float* w_out = (const float*)d_in[3];
  float* out = (float*)d_out;
  char* ws = (char*)d_ws;
  unsigned short* wqkvT = (unsigned short*)(ws);                // 6291456 B
  unsigned short* woutT = (unsigned short*)(ws + 6291456);      // 2097152 B
  unsigned short* normed = (unsigned short*)(ws + 8388608);     // 8388608 B
  unsigned short* qbuf = (unsigned short*)(ws + 16777216);      // 8388608 B
  unsigned short* kbuf = (unsigned short*)(ws + 25165824);      // 8388608 B
  unsigned short* vtbuf = (unsigned short*)(ws + 33554432);     // 8388608 B (permuted V^T)
  unsigned short* aout = (unsigned short*)(ws + 41943040);      // 8388608 B

  hipLaunchKernelGGL(prep_kernel, dim3(8192), dim3(256), 0, stream,
                     x, gamma, w_qkv, w_out, normed, wqkvT, woutT);
  hipLaunchKernelGGL(qkv_gemm_kernel, dim3((BATCH * SEQ / BM) * (NQKV / BN)), dim3(256), 0,
                     stream, normed, wqkvT, qbuf, kbuf, vtbuf);
  hipLaunchKernelGGL(attn_kernel, dim3(BATCH * NHEAD * 32), dim3(256), 0, stream,
                     qbuf, kbuf, vtbuf, aout);
  hipLaunchKernelGGL(out_gemm_kernel, dim3((BATCH * SEQ / BM) * (DMODEL / BN)), dim3(256), 0,
                     stream, aout, woutT, out);
}